// Round 7
// baseline (223.742 us; speedup 1.0000x reference)
//
#include <hip/hip_runtime.h>
#include <math.h>

// CrossAttention B=2,S=2048,E=1024,H=16,Dh=64,NC=768 — fp32 in/out.
// R9: XCD-colocating swizzle for GEMM grids + combine fused into gemm_out.
// R13 post-mortem (ran): counted-vmcnt pipeline = 48.3us vs R11 drain-0 =
//   46.4us — same MfmaUtil/VALUBusy/occupancy fingerprint. Barrier drain was
//   NOT the bottleneck; DMA already hidden. Limiter = per-wave serial chain
//   (QK MFMAs -> exp2 -> transpose -> PV) with only ~30% occupancy to
//   overlap it.
// R16: attn reverted to R11 64-row dual-chain body (proven) + KV-split x4:
//   grid 2048 (32 hidx x 16 qb x 4 split), 8 iters x 64 rows per block.
//   More independent blocks/CU (4->5, LDS 32KB cap) to raise TLP.
//   Zero extra workspace: p2 aliases xb (8MB), p3 aliases cb+Wqt (8MB,
//   ends exactly at Wkt), lsum1 aliases Wkt (all dead after gemm_qkv;
//   stream-ordered). gemm_out combines 4 partials + 2 lsum arrays.
// prep/gemm_qkv unchanged.

namespace {

typedef short bfr __attribute__((ext_vector_type(8)));   // 8 bf16 = 4 VGPR
typedef short s4v __attribute__((ext_vector_type(4)));
typedef unsigned u4v __attribute__((ext_vector_type(4)));
typedef float accf __attribute__((ext_vector_type(16)));

#define MFMA32(a, b, c) __builtin_amdgcn_mfma_f32_32x32x16_bf16(a, b, c, 0, 0, 0)

__device__ inline short f2bf(float f) {  // RNE
    unsigned u = __float_as_uint(f);
    u += 0x7fffu + ((u >> 16) & 1u);
    return (short)(u >> 16);
}
__device__ inline float bf2f(short s) {
    return __uint_as_float(((unsigned)(unsigned short)s) << 16);
}
__device__ inline float fexp2(float x) { return __builtin_amdgcn_exp2f(x); }
__device__ inline accf zero16() {
    accf z;
#pragma unroll
    for (int i = 0; i < 16; ++i) z[i] = 0.f;
    return z;
}
__device__ inline void dma16(const void* g, void* l) {
    __builtin_amdgcn_global_load_lds(
        (const __attribute__((address_space(1))) void*)g,
        (__attribute__((address_space(3))) void*)l, 16, 0, 0);
}

// ---------- prep: tobf (x,ctx) + all 4 weight transposes, one dispatch ----
__global__ __launch_bounds__(256) void prep(
    const float* __restrict__ x, const float* __restrict__ ctx,
    short* __restrict__ xb, short* __restrict__ cb,
    const float* __restrict__ Wq, const float* __restrict__ Wk,
    const float* __restrict__ Wv, const float* __restrict__ Wo,
    short* __restrict__ Wqt, short* __restrict__ Wkt,
    short* __restrict__ Wvt, short* __restrict__ Wot) {
    __shared__ short t[64][68];
    const int bx = blockIdx.x;
    if (bx < 7168) {  // elementwise fp32->bf16
        int i = bx * 256 + threadIdx.x;
        if (i < 1048576) {
            float4 v = ((const float4*)x)[i];
            s4v p = {f2bf(v.x), f2bf(v.y), f2bf(v.z), f2bf(v.w)};
            ((s4v*)xb)[i] = p;
        } else {
            int j = i - 1048576;
            float4 v = ((const float4*)ctx)[j];
            s4v p = {f2bf(v.x), f2bf(v.y), f2bf(v.z), f2bf(v.w)};
            ((s4v*)cb)[j] = p;
        }
        return;
    }
    const int idx = bx - 7168;  // 0..1023
    const int z = idx >> 8, gy = (idx >> 4) & 15, gx = idx & 15;
    const float* W;
    short* Wt;
    int K;
    switch (z) {
        case 0: W = Wq; Wt = Wqt; K = 1024; break;
        case 1: W = Wk; Wt = Wkt; K = 768; break;
        case 2: W = Wv; Wt = Wvt; K = 768; break;
        default: W = Wo; Wt = Wot; K = 1024; break;
    }
    const int k0 = gy * 64;
    if (k0 >= K) return;
    const int tid = threadIdx.x;
    const int n0 = gx * 64;
    const int kr = tid >> 4, nc = (tid & 15) * 4;
#pragma unroll
    for (int rep = 0; rep < 4; ++rep) {
        int k = kr + rep * 16;
        float4 v = *(const float4*)&W[(size_t)(k0 + k) * 1024 + n0 + nc];
        t[nc + 0][k] = f2bf(v.x);
        t[nc + 1][k] = f2bf(v.y);
        t[nc + 2][k] = f2bf(v.z);
        t[nc + 3][k] = f2bf(v.w);
    }
    __syncthreads();
    const int nr = tid >> 4, kc = (tid & 15) * 4;
#pragma unroll
    for (int rep = 0; rep < 4; ++rep) {
        int n = nr + rep * 16;
        s4v p = {t[n][kc], t[n][kc + 1], t[n][kc + 2], t[n][kc + 3]};
        *(s4v*)&Wt[(size_t)(n0 + n) * K + k0 + kc] = p;
    }
}

// ---------- fused Q/K/V projection GEMM, XCD-swizzled 1D grid (768) -------
// bid: z = bid>>8; local = bid&255; m = local&31, n = local>>5
// -> bid%8 == m%8: the 8 n-blocks sharing an A-tile colocate on one XCD.
__global__ __launch_bounds__(256) void gemm_qkv(
    const short* __restrict__ xb, const short* __restrict__ cb,
    const short* __restrict__ Wqt, const short* __restrict__ Wkt,
    const short* __restrict__ Wvt, const float* __restrict__ bq,
    const float* __restrict__ bk, const float* __restrict__ bv,
    short* __restrict__ Qf, short* __restrict__ Kf, short* __restrict__ Vt,
    float qscale) {
    const int bid = blockIdx.x;
    const int z = bid >> 8;
    const int local = bid & 255;
    const short* A  = (z == 0) ? xb : cb;
    const short* Bt = (z == 0) ? Wqt : ((z == 1) ? Wkt : Wvt);
    const float* bias = (z == 0) ? bq : ((z == 1) ? bk : bv);
    const int K = (z == 0) ? 1024 : 768;
    const int NIT = K / 32;
    const float scale = (z == 0) ? qscale : 1.f;
    short* out = (z == 0) ? Qf : ((z == 1) ? Kf : Vt);

    __shared__ short As[8192];  // 2 x 4096 (double buffer)
    __shared__ short Bs[8192];
    const int t = threadIdx.x, lane = t & 63, w = t >> 6;
    const int lm = lane & 31, h2 = lane >> 5;
    const int wm = w & 1, wn = w >> 1;
    const int m0 = (local & 31) * 128, n0 = (local >> 5) * 128;

    // staging: slot t holds global chunk sigma(t) = t ^ ((t>>3)&7)
    const int st = t ^ ((t >> 3) & 7);
    const int srow = st >> 2, scol = (st & 3) * 8;
    const short* ga = A + (size_t)(m0 + srow) * K + scol;
    const short* gb = Bt + (size_t)(n0 + srow) * K + scol;

    // read: slot = chunk ^ xorv, chunk = row*4 + colchunk
    const int xorv = (lm >> 1) & 7;
    const int rA0 = wm * 64 + lm, rB0 = wn * 64 + lm;

    accf acc[2][2] = {zero16(), zero16(), zero16(), zero16()};

    // prologue: stage iter 0 into buf 0
    dma16(ga, &As[w * 512]);
    dma16(ga + (size_t)64 * K, &As[2048 + w * 512]);
    dma16(gb, &Bs[w * 512]);
    dma16(gb + (size_t)64 * K, &Bs[2048 + w * 512]);

#pragma unroll 1
    for (int it = 0; it < NIT; ++it) {
        const int p = it & 1;
        __syncthreads();  // drains DMA for buf p (vmcnt0 before s_barrier)
        if (it + 1 < NIT) {
            const int kt = (it + 1) * 32;
            short* lA = &As[(1 - p) * 4096 + w * 512];
            short* lB = &Bs[(1 - p) * 4096 + w * 512];
            dma16(ga + kt, lA);
            dma16(ga + (size_t)64 * K + kt, lA + 2048);
            dma16(gb + kt, lB);
            dma16(gb + (size_t)64 * K + kt, lB + 2048);
        }
        const short* bA = &As[p * 4096];
        const short* bB = &Bs[p * 4096];
#pragma unroll
        for (int kk8 = 0; kk8 < 4; kk8 += 2) {
            bfr a0 = *(const bfr*)&bA[((rA0 * 4 + h2 + kk8) ^ xorv) * 8];
            bfr a1 = *(const bfr*)&bA[(((rA0 + 32) * 4 + h2 + kk8) ^ xorv) * 8];
            bfr b0 = *(const bfr*)&bB[((rB0 * 4 + h2 + kk8) ^ xorv) * 8];
            bfr b1 = *(const bfr*)&bB[(((rB0 + 32) * 4 + h2 + kk8) ^ xorv) * 8];
            acc[0][0] = MFMA32(a0, b0, acc[0][0]);
            acc[0][1] = MFMA32(a0, b1, acc[0][1]);
            acc[1][0] = MFMA32(a1, b0, acc[1][0]);
            acc[1][1] = MFMA32(a1, b1, acc[1][1]);
        }
    }

#pragma unroll
    for (int nt = 0; nt < 2; ++nt) {
        const int n = n0 + wn * 64 + nt * 32 + lm;
        const float bn = bias[n];
        const int hh = n >> 6, dd = n & 63;
#pragma unroll
        for (int mt = 0; mt < 2; ++mt) {
            const int mbase = m0 + wm * 64 + mt * 32 + 4 * h2;
            if (z != 2) {
                const int cb2 = (dd >> 4) * 512 + ((dd >> 3) & 1) * 256 + (dd & 7);
#pragma unroll
                for (int r = 0; r < 16; ++r) {
                    const int m = mbase + (r & 3) + 8 * (r >> 2);
                    const int bb = m >> 11, q = m & 2047;
                    float v = (acc[mt][nt][r] + bn) * scale;
                    out[((size_t)((bb * 16 + hh) * 64 + (q >> 5))) * 2048 +
                        cb2 + (q & 31) * 8] = f2bf(v);
                }
            } else {
                const int dblk = dd >> 5, lmv = dd & 31;
#pragma unroll
                for (int g = 0; g < 4; ++g) {
                    const int m = mbase + 8 * g;
                    const int bb = m >> 11, s = m & 2047;
                    const int kvt = s >> 6, kc = (s >> 4) & 3;
                    const int h2v = (s >> 3) & 1, j0 = s & 7;
                    s4v p = {f2bf(acc[mt][nt][4 * g + 0] + bn),
                             f2bf(acc[mt][nt][4 * g + 1] + bn),
                             f2bf(acc[mt][nt][4 * g + 2] + bn),
                             f2bf(acc[mt][nt][4 * g + 3] + bn)};
                    *(s4v*)(out +
                            ((size_t)(((bb * 16 + hh) * 32 + kvt) * 2 + dblk)) * 2048 +
                            kc * 512 + h2v * 256 + lmv * 8 + j0) = p;
                }
            }
        }
    }
}

// ---------- output GEMM with fused 4-way combine (512 thr, 8 waves) -------
// A-tile = (p0+p1+p2+p3)*inv staged via explicit loads + ds_write (same
// swizzled slots); B via DMA. 1D grid 256, XCD swizzle m = bid&31.
__global__ __launch_bounds__(512) void gemm_out(
    const short* __restrict__ p0, const short* __restrict__ p1,
    const short* __restrict__ p2, const short* __restrict__ p3,
    const float* __restrict__ lsum0, const float* __restrict__ lsum1,
    const short* __restrict__ Bt, const float* __restrict__ bias,
    float* __restrict__ out) {
    constexpr int K = 1024, NIT = 32;
    __shared__ short As[8192];  // 2 x 4096
    __shared__ short Bs[8192];
    const int t = threadIdx.x, lane = t & 63, w = t >> 6;  // w 0..7
    const int lm = lane & 31, h2 = lane >> 5;
    const int wm = w & 1, wn = w >> 1;
    const int bid = blockIdx.x;
    const int m0 = (bid & 31) * 128, n0 = (bid >> 5) * 128;

    const int st = t ^ ((t >> 3) & 7);
    const int srow = st >> 2, scol = (st & 3) * 8;  // 512 thr cover full tile
    const int gm = m0 + srow;
    const int b = gm >> 11, q = gm & 2047;
    const short* pa0 = p0 + (size_t)gm * 1024 + scol;
    const short* pa1 = p1 + (size_t)gm * 1024 + scol;
    const short* pa2 = p2 + (size_t)gm * 1024 + scol;
    const short* pa3 = p3 + (size_t)gm * 1024 + scol;
    const short* gb = Bt + (size_t)(n0 + srow) * K + scol;

    float inv[16];
#pragma unroll
    for (int h = 0; h < 16; ++h) {
        float l = lsum0[((size_t)b * 16 + h) * 2048 + q] +
                  lsum0[((size_t)(2 + b) * 16 + h) * 2048 + q] +
                  lsum1[((size_t)b * 16 + h) * 2048 + q] +
                  lsum1[((size_t)(2 + b) * 16 + h) * 2048 + q];
        inv[h] = 1.f / l;
    }

    const int xorv = (lm >> 1) & 7;
    const int rA0 = wm * 64 + lm, rB0 = wn * 32 + lm;

    accf acc[2] = {zero16(), zero16()};

    // prologue: stage iter 0 (B via DMA, A via load+combine+ds_write)
    dma16(gb, &Bs[w * 512]);
    {
        bfr v0 = *(const bfr*)pa0;
        bfr v1 = *(const bfr*)pa1;
        bfr v2 = *(const bfr*)pa2;
        bfr v3 = *(const bfr*)pa3;
        const float iv = inv[0];
        bfr pk;
#pragma unroll
        for (int j = 0; j < 8; ++j)
            pk[j] = f2bf((bf2f(v0[j]) + bf2f(v1[j]) + bf2f(v2[j]) +
                          bf2f(v3[j])) * iv);
        *(bfr*)&As[t * 8] = pk;
    }

#pragma unroll 1
    for (int it = 0; it < NIT; ++it) {
        const int p = it & 1;
        __syncthreads();  // drains buf-p DMA + ds_writes
        bfr v0, v1, v2, v3;
        const bool nxt = (it + 1 < NIT);
        if (nxt) {
            const int ktn = (it + 1) * 32;
            dma16(gb + ktn, &Bs[(1 - p) * 4096 + w * 512]);
            v0 = *(const bfr*)(pa0 + ktn);
            v1 = *(const bfr*)(pa1 + ktn);
            v2 = *(const bfr*)(pa2 + ktn);
            v3 = *(const bfr*)(pa3 + ktn);
        }
        const short* bA = &As[p * 4096];
        const short* bB = &Bs[p * 4096];
#pragma unroll
        for (int kk8 = 0; kk8 < 4; kk8 += 2) {
            bfr a0 = *(const bfr*)&bA[((rA0 * 4 + h2 + kk8) ^ xorv) * 8];
            bfr a1 = *(const bfr*)&bA[(((rA0 + 32) * 4 + h2 + kk8) ^ xorv) * 8];
            bfr b0 = *(const bfr*)&bB[((rB0 * 4 + h2 + kk8) ^ xorv) * 8];
            acc[0] = MFMA32(a0, b0, acc[0]);
            acc[1] = MFMA32(a1, b0, acc[1]);
        }
        if (nxt) {
            const float iv = inv[(it + 1) >> 1];  // h = kt>>6, iter-uniform
            bfr pk;
#pragma unroll
            for (int j = 0; j < 8; ++j)
                pk[j] = f2bf((bf2f(v0[j]) + bf2f(v1[j]) + bf2f(v2[j]) +
                              bf2f(v3[j])) * iv);
            *(bfr*)&As[(1 - p) * 4096 + t * 8] = pk;
        }
    }

    const int n = n0 + wn * 32 + lm;
    const float bn = bias[n];
#pragma unroll
    for (int mt = 0; mt < 2; ++mt) {
        const int mbase = m0 + wm * 64 + mt * 32 + 4 * h2;
#pragma unroll
        for (int r = 0; r < 16; ++r) {
            const int m = mbase + (r & 3) + 8 * (r >> 2);
            out[(size_t)m * 1024 + n] = acc[mt][r] + bn;
        }
    }
}

// ---------- flash attention: R11 64-row dual-chain body, KV-split x4 ------
// grid 2048: hidx = bid&31, qs = bid>>5, split = qs&3, qb = qs>>2.
// Each block: 512 KV rows = 8 iters x 64 rows, 2x16KB LDS double buffer,
// __syncthreads drain per iter (proven structure, 46.4us at split-2).
__global__ __launch_bounds__(256, 3) void attn(
    const short* __restrict__ Qf, const short* __restrict__ Kf,
    const short* __restrict__ Vt, short* __restrict__ pt0,
    short* __restrict__ pt1, short* __restrict__ pt2,
    short* __restrict__ pt3, float* __restrict__ lsum0,
    float* __restrict__ lsum1) {
    __shared__ short smem[16384];  // 2 bufs x (K 4KB + V 4KB) = 32 KB
    const int bid = blockIdx.x;
    const int hidx = bid & 31, qs = bid >> 5;
    const int split = qs & 3, qb = qs >> 2;
    const int b = hidx >> 4, h = hidx & 15;
    const int lane = threadIdx.x & 63, wv = threadIdx.x >> 6;
    const int lm = lane & 31, h2 = lane >> 5;
    const bool hb = h2 != 0;
    const int q0 = qb * 128 + wv * 32;

    const short* qbase =
        Qf + ((size_t)(hidx * 64 + (q0 >> 5))) * 2048 + lane * 8;
    bfr qf[4];
#pragma unroll
    for (int kc = 0; kc < 4; ++kc) qf[kc] = *(const bfr*)(qbase + kc * 512);

    const short* khead = Kf + (size_t)hidx * 131072 + split * 32768;
    const short* vhead = Vt + (size_t)hidx * 131072 + split * 32768;
    const short* gsrc =
        ((wv < 2) ? (khead + wv * 2048) : (vhead + (wv - 2) * 2048)) + lane * 8;

#pragma unroll
    for (int i = 0; i < 4; ++i)
        dma16(gsrc + i * 512, &smem[wv * 2048 + i * 512]);

    accf oa0 = zero16(), oa1 = zero16();
    float la0 = 0.f, la1 = 0.f;

#pragma unroll 1
    for (int it = 0; it < 8; ++it) {
        const int p = it & 1;
        __syncthreads();  // buf p DMA drained (vmcnt(0) before s_barrier)
        if (it + 1 < 8) {
            const short* gn = gsrc + (size_t)(it + 1) * 4096;
            short* ln = &smem[(1 - p) * 8192 + wv * 2048];
#pragma unroll
            for (int i = 0; i < 4; ++i) dma16(gn + i * 512, ln + i * 512);
        }
        const short* kb = &smem[p * 8192];
        bfr kf0[4], kf1[4], vf0[4], vf1[4];
#pragma unroll
        for (int kc = 0; kc < 4; ++kc) {
            kf0[kc] = *(const bfr*)&kb[kc * 512 + lane * 8];
            kf1[kc] = *(const bfr*)&kb[2048 + kc * 512 + lane * 8];
            vf0[kc] = *(const bfr*)&kb[4096 + kc * 512 + lane * 8];
            vf1[kc] = *(const bfr*)&kb[6144 + kc * 512 + lane * 8];
        }
        accf s0 = zero16(), s1 = zero16();
#pragma unroll
        for (int kc = 0; kc < 4; ++kc) {
            s0 = MFMA32(kf0[kc], qf[kc], s0);
            s1 = MFMA32(kf1[kc], qf[kc], s1);
        }

#pragma unroll
        for (int i = 0; i < 16; ++i) s0[i] = fexp2(s0[i]);
#pragma unroll
        for (int i = 0; i < 16; ++i) s1[i] = fexp2(s1[i]);
#pragma unroll
        for (int i = 0; i < 16; ++i) {
            if (i & 1) la1 += s0[i] + s1[i];
            else       la0 += s0[i] + s1[i];
        }

        // packed half-swap transpose
        bfr pb[4];
#pragma unroll
        for (int kc = 0; kc < 4; ++kc) {
            const accf& s = (kc < 2) ? s0 : s1;
            const int base = 8 * (kc & 1);
            unsigned Lw0 = __builtin_amdgcn_perm(__float_as_uint(s[base + 1]),
                                                 __float_as_uint(s[base + 0]),
                                                 0x07060302u);
            unsigned Lw1 = __builtin_amdgcn_perm(__float_as_uint(s[base + 3]),
                                                 __float_as_uint(s[base + 2]),
                                                 0x07060302u);
            unsigned Hw0 = __builtin_amdgcn_perm(__float_as_uint(s[base + 5]),
                                                 __float_as_uint(s[base + 4]),
                                                 0x07060302u);
            unsigned Hw1 = __builtin_amdgcn_perm(__float_as_uint(s[base + 7]),
                                                 __float_as_uint(s[base + 6]),
                                                 0x07060302u);
            unsigned c0 = hb ? Lw0 : Hw0;
            unsigned c1 = hb ? Lw1 : Hw1;
            unsigned r0 = (unsigned)__shfl_xor((int)c0, 32);
            unsigned r1 = (unsigned)__shfl_xor((int)c1, 32);
            u4v pw = {hb ? r0 : Lw0, hb ? r1 : Lw1,
                      hb ? Hw0 : r0, hb ? Hw1 : r1};
            pb[kc] = __builtin_bit_cast(bfr, pw);
        }

#pragma unroll
        for (int kc = 0; kc < 4; ++kc) {
            oa0 = MFMA32(vf0[kc], pb[kc], oa0);
            oa1 = MFMA32(vf1[kc], pb[kc], oa1);
        }
    }

    float ls = la0 + la1;
    ls += __shfl_xor(ls, 32);
    float* lp = (split < 2) ? lsum0 : lsum1;
    const int sb = split & 1;
    if (!hb) lp[((size_t)(sb * 2 + b) * 16 + h) * 2048 + q0 + lm] = ls;

    short* psel = (split == 0) ? pt0
                : (split == 1) ? pt1
                : (split == 2) ? pt2 : pt3;
    short* orow = psel + (size_t)(b * 2048 + q0 + lm) * 1024 + h * 64;
#pragma unroll
    for (int dt = 0; dt < 2; ++dt) {
        const accf& oa = dt ? oa1 : oa0;
#pragma unroll
        for (int g = 0; g < 4; ++g) {
            const int d0 = dt * 32 + 4 * h2 + 8 * g;
            s4v p = {f2bf(oa[4 * g + 0]), f2bf(oa[4 * g + 1]),
                     f2bf(oa[4 * g + 2]), f2bf(oa[4 * g + 3])};
            *(s4v*)(orow + d0) = p;
        }
    }
}

}  // namespace

extern "C" void kernel_launch(void* const* d_in, const int* in_sizes, int n_in,
                              void* d_out, int out_size, void* d_ws,
                              size_t ws_size, hipStream_t stream) {
    const float* x   = (const float*)d_in[0];
    const float* ctx = (const float*)d_in[1];
    const float* Wq  = (const float*)d_in[2];
    const float* bq  = (const float*)d_in[3];
    const float* Wk  = (const float*)d_in[4];
    const float* bk  = (const float*)d_in[5];
    const float* Wv  = (const float*)d_in[6];
    const float* bv  = (const float*)d_in[7];
    const float* Wo  = (const float*)d_in[8];
    const float* bo  = (const float*)d_in[9];

    short* xb  = (short*)d_ws;
    short* cb  = xb + (size_t)4096 * 1024;
    short* Wqt = cb + (size_t)4096 * 768;
    short* Wkt = Wqt + (size_t)1024 * 1024;
    short* Wvt = Wkt + (size_t)1024 * 768;
    short* Wot = Wvt + (size_t)1024 * 768;
    short* Qf  = Wot + (size_t)1024 * 1024;  // frag-order, pre-scaled
    short* Kf  = Qf + (size_t)4096 * 1024;   // frag-order
    short* Vt  = Kf + (size_t)4096 * 1024;   // frag-order V^T
    short* p0  = Vt + (size_t)4096 * 1024;   // split partials (unnormalized)
    short* p1  = p0 + (size_t)4096 * 1024;
    float* lsum0 = (float*)(p1 + (size_t)4096 * 1024);  // [2][2][16][2048]
    // aliases into regions dead after gemm_qkv (stream-ordered):
    short* p2 = xb;              // 8 MB
    short* p3 = cb;              // cb(6MB)+Wqt(2MB) = exactly 8 MB, ends at Wkt
    float* lsum1 = (float*)Wkt;  // 0.5 MB within Wkt's 1.5 MB

    prep<<<8192, 256, 0, stream>>>(x, ctx, xb, cb, Wq, Wk, Wv, Wo,
                                   Wqt, Wkt, Wvt, Wot);

    const float qscale = 0.125f * 1.44269504088896f;
    gemm_qkv<<<768, 256, 0, stream>>>(xb, cb, Wqt, Wkt, Wvt,
                                      bq, bk, bv, Qf, Kf, Vt, qscale);

    attn<<<2048, 256, 0, stream>>>(Qf, Kf, Vt, p0, p1, p2, p3, lsum0, lsum1);

    gemm_out<<<256, 512, 0, stream>>>(p0, p1, p2, p3, lsum0, lsum1,
                                      Wot, bo, (float*)d_out);
}

// Round 8
// 221.405 us; speedup vs baseline: 1.0106x; 1.0106x over previous
//
#include <hip/hip_runtime.h>
#include <math.h>

// CrossAttention B=2,S=2048,E=1024,H=16,Dh=64,NC=768 — fp32 in/out.
// R9: XCD-colocating swizzle for GEMM grids + combine fused into gemm_out.
// R13 (ran): counted-vmcnt attn = 48.3us vs R11 drain-0 46.4 — drain not the
//   bottleneck. R16 (ran): KV-split x4 = 47.6us, occupancy UNCHANGED ~30%,
//   total 223.7 (doubled partial traffic) — TLP not the bottleneck either.
//   attn plateau ~46us is intrinsic to this 64-row 4-wave structure.
// R17: full revert to R11 (216.4us proven) + INSTRUMENTATION: attn launched
//   as two 512-block dispatches (q-halves; blocks independent => identity).
//   Each half ~23us < gemm_qkv/gemm_out/prep, so the next rocprof top-5
//   finally exposes the other ~170us of runtime with counters. Next round
//   targets whichever non-attn kernel dominates.

namespace {

typedef short bfr __attribute__((ext_vector_type(8)));   // 8 bf16 = 4 VGPR
typedef short s4v __attribute__((ext_vector_type(4)));
typedef unsigned u4v __attribute__((ext_vector_type(4)));
typedef float accf __attribute__((ext_vector_type(16)));

#define MFMA32(a, b, c) __builtin_amdgcn_mfma_f32_32x32x16_bf16(a, b, c, 0, 0, 0)

__device__ inline short f2bf(float f) {  // RNE
    unsigned u = __float_as_uint(f);
    u += 0x7fffu + ((u >> 16) & 1u);
    return (short)(u >> 16);
}
__device__ inline float bf2f(short s) {
    return __uint_as_float(((unsigned)(unsigned short)s) << 16);
}
__device__ inline float fexp2(float x) { return __builtin_amdgcn_exp2f(x); }
__device__ inline accf zero16() {
    accf z;
#pragma unroll
    for (int i = 0; i < 16; ++i) z[i] = 0.f;
    return z;
}
__device__ inline void dma16(const void* g, void* l) {
    __builtin_amdgcn_global_load_lds(
        (const __attribute__((address_space(1))) void*)g,
        (__attribute__((address_space(3))) void*)l, 16, 0, 0);
}

// ---------- prep: tobf (x,ctx) + all 4 weight transposes, one dispatch ----
__global__ __launch_bounds__(256) void prep(
    const float* __restrict__ x, const float* __restrict__ ctx,
    short* __restrict__ xb, short* __restrict__ cb,
    const float* __restrict__ Wq, const float* __restrict__ Wk,
    const float* __restrict__ Wv, const float* __restrict__ Wo,
    short* __restrict__ Wqt, short* __restrict__ Wkt,
    short* __restrict__ Wvt, short* __restrict__ Wot) {
    __shared__ short t[64][68];
    const int bx = blockIdx.x;
    if (bx < 7168) {  // elementwise fp32->bf16
        int i = bx * 256 + threadIdx.x;
        if (i < 1048576) {
            float4 v = ((const float4*)x)[i];
            s4v p = {f2bf(v.x), f2bf(v.y), f2bf(v.z), f2bf(v.w)};
            ((s4v*)xb)[i] = p;
        } else {
            int j = i - 1048576;
            float4 v = ((const float4*)ctx)[j];
            s4v p = {f2bf(v.x), f2bf(v.y), f2bf(v.z), f2bf(v.w)};
            ((s4v*)cb)[j] = p;
        }
        return;
    }
    const int idx = bx - 7168;  // 0..1023
    const int z = idx >> 8, gy = (idx >> 4) & 15, gx = idx & 15;
    const float* W;
    short* Wt;
    int K;
    switch (z) {
        case 0: W = Wq; Wt = Wqt; K = 1024; break;
        case 1: W = Wk; Wt = Wkt; K = 768; break;
        case 2: W = Wv; Wt = Wvt; K = 768; break;
        default: W = Wo; Wt = Wot; K = 1024; break;
    }
    const int k0 = gy * 64;
    if (k0 >= K) return;
    const int tid = threadIdx.x;
    const int n0 = gx * 64;
    const int kr = tid >> 4, nc = (tid & 15) * 4;
#pragma unroll
    for (int rep = 0; rep < 4; ++rep) {
        int k = kr + rep * 16;
        float4 v = *(const float4*)&W[(size_t)(k0 + k) * 1024 + n0 + nc];
        t[nc + 0][k] = f2bf(v.x);
        t[nc + 1][k] = f2bf(v.y);
        t[nc + 2][k] = f2bf(v.z);
        t[nc + 3][k] = f2bf(v.w);
    }
    __syncthreads();
    const int nr = tid >> 4, kc = (tid & 15) * 4;
#pragma unroll
    for (int rep = 0; rep < 4; ++rep) {
        int n = nr + rep * 16;
        s4v p = {t[n][kc], t[n][kc + 1], t[n][kc + 2], t[n][kc + 3]};
        *(s4v*)&Wt[(size_t)(n0 + n) * K + k0 + kc] = p;
    }
}

// ---------- fused Q/K/V projection GEMM, XCD-swizzled 1D grid (768) -------
// bid: z = bid>>8; local = bid&255; m = local&31, n = local>>5
// -> bid%8 == m%8: the 8 n-blocks sharing an A-tile colocate on one XCD.
__global__ __launch_bounds__(256) void gemm_qkv(
    const short* __restrict__ xb, const short* __restrict__ cb,
    const short* __restrict__ Wqt, const short* __restrict__ Wkt,
    const short* __restrict__ Wvt, const float* __restrict__ bq,
    const float* __restrict__ bk, const float* __restrict__ bv,
    short* __restrict__ Qf, short* __restrict__ Kf, short* __restrict__ Vt,
    float qscale) {
    const int bid = blockIdx.x;
    const int z = bid >> 8;
    const int local = bid & 255;
    const short* A  = (z == 0) ? xb : cb;
    const short* Bt = (z == 0) ? Wqt : ((z == 1) ? Wkt : Wvt);
    const float* bias = (z == 0) ? bq : ((z == 1) ? bk : bv);
    const int K = (z == 0) ? 1024 : 768;
    const int NIT = K / 32;
    const float scale = (z == 0) ? qscale : 1.f;
    short* out = (z == 0) ? Qf : ((z == 1) ? Kf : Vt);

    __shared__ short As[8192];  // 2 x 4096 (double buffer)
    __shared__ short Bs[8192];
    const int t = threadIdx.x, lane = t & 63, w = t >> 6;
    const int lm = lane & 31, h2 = lane >> 5;
    const int wm = w & 1, wn = w >> 1;
    const int m0 = (local & 31) * 128, n0 = (local >> 5) * 128;

    // staging: slot t holds global chunk sigma(t) = t ^ ((t>>3)&7)
    const int st = t ^ ((t >> 3) & 7);
    const int srow = st >> 2, scol = (st & 3) * 8;
    const short* ga = A + (size_t)(m0 + srow) * K + scol;
    const short* gb = Bt + (size_t)(n0 + srow) * K + scol;

    // read: slot = chunk ^ xorv, chunk = row*4 + colchunk
    const int xorv = (lm >> 1) & 7;
    const int rA0 = wm * 64 + lm, rB0 = wn * 64 + lm;

    accf acc[2][2] = {zero16(), zero16(), zero16(), zero16()};

    // prologue: stage iter 0 into buf 0
    dma16(ga, &As[w * 512]);
    dma16(ga + (size_t)64 * K, &As[2048 + w * 512]);
    dma16(gb, &Bs[w * 512]);
    dma16(gb + (size_t)64 * K, &Bs[2048 + w * 512]);

#pragma unroll 1
    for (int it = 0; it < NIT; ++it) {
        const int p = it & 1;
        __syncthreads();  // drains DMA for buf p (vmcnt0 before s_barrier)
        if (it + 1 < NIT) {
            const int kt = (it + 1) * 32;
            short* lA = &As[(1 - p) * 4096 + w * 512];
            short* lB = &Bs[(1 - p) * 4096 + w * 512];
            dma16(ga + kt, lA);
            dma16(ga + (size_t)64 * K + kt, lA + 2048);
            dma16(gb + kt, lB);
            dma16(gb + (size_t)64 * K + kt, lB + 2048);
        }
        const short* bA = &As[p * 4096];
        const short* bB = &Bs[p * 4096];
#pragma unroll
        for (int kk8 = 0; kk8 < 4; kk8 += 2) {
            bfr a0 = *(const bfr*)&bA[((rA0 * 4 + h2 + kk8) ^ xorv) * 8];
            bfr a1 = *(const bfr*)&bA[(((rA0 + 32) * 4 + h2 + kk8) ^ xorv) * 8];
            bfr b0 = *(const bfr*)&bB[((rB0 * 4 + h2 + kk8) ^ xorv) * 8];
            bfr b1 = *(const bfr*)&bB[(((rB0 + 32) * 4 + h2 + kk8) ^ xorv) * 8];
            acc[0][0] = MFMA32(a0, b0, acc[0][0]);
            acc[0][1] = MFMA32(a0, b1, acc[0][1]);
            acc[1][0] = MFMA32(a1, b0, acc[1][0]);
            acc[1][1] = MFMA32(a1, b1, acc[1][1]);
        }
    }

#pragma unroll
    for (int nt = 0; nt < 2; ++nt) {
        const int n = n0 + wn * 64 + nt * 32 + lm;
        const float bn = bias[n];
        const int hh = n >> 6, dd = n & 63;
#pragma unroll
        for (int mt = 0; mt < 2; ++mt) {
            const int mbase = m0 + wm * 64 + mt * 32 + 4 * h2;
            if (z != 2) {
                const int cb2 = (dd >> 4) * 512 + ((dd >> 3) & 1) * 256 + (dd & 7);
#pragma unroll
                for (int r = 0; r < 16; ++r) {
                    const int m = mbase + (r & 3) + 8 * (r >> 2);
                    const int bb = m >> 11, q = m & 2047;
                    float v = (acc[mt][nt][r] + bn) * scale;
                    out[((size_t)((bb * 16 + hh) * 64 + (q >> 5))) * 2048 +
                        cb2 + (q & 31) * 8] = f2bf(v);
                }
            } else {
                const int dblk = dd >> 5, lmv = dd & 31;
#pragma unroll
                for (int g = 0; g < 4; ++g) {
                    const int m = mbase + 8 * g;
                    const int bb = m >> 11, s = m & 2047;
                    const int kvt = s >> 6, kc = (s >> 4) & 3;
                    const int h2v = (s >> 3) & 1, j0 = s & 7;
                    s4v p = {f2bf(acc[mt][nt][4 * g + 0] + bn),
                             f2bf(acc[mt][nt][4 * g + 1] + bn),
                             f2bf(acc[mt][nt][4 * g + 2] + bn),
                             f2bf(acc[mt][nt][4 * g + 3] + bn)};
                    *(s4v*)(out +
                            ((size_t)(((bb * 16 + hh) * 32 + kvt) * 2 + dblk)) * 2048 +
                            kc * 512 + h2v * 256 + lmv * 8 + j0) = p;
                }
            }
        }
    }
}

// ---------- output GEMM with fused combine (512 thr, 8 waves) ----------
// A-tile = (p0+p1)*inv staged via explicit loads + ds_write (same swizzled
// slots); B via DMA. 1D grid 256, XCD swizzle m = bid&31.
__global__ __launch_bounds__(512) void gemm_out(
    const short* __restrict__ p0, const short* __restrict__ p1,
    const float* __restrict__ lsum, const short* __restrict__ Bt,
    const float* __restrict__ bias, float* __restrict__ out) {
    constexpr int K = 1024, NIT = 32;
    __shared__ short As[8192];  // 2 x 4096
    __shared__ short Bs[8192];
    const int t = threadIdx.x, lane = t & 63, w = t >> 6;  // w 0..7
    const int lm = lane & 31, h2 = lane >> 5;
    const int wm = w & 1, wn = w >> 1;
    const int bid = blockIdx.x;
    const int m0 = (bid & 31) * 128, n0 = (bid >> 5) * 128;

    const int st = t ^ ((t >> 3) & 7);
    const int srow = st >> 2, scol = (st & 3) * 8;  // 512 thr cover full tile
    const int gm = m0 + srow;
    const int b = gm >> 11, q = gm & 2047;
    const short* pa0 = p0 + (size_t)gm * 1024 + scol;
    const short* pa1 = p1 + (size_t)gm * 1024 + scol;
    const short* gb = Bt + (size_t)(n0 + srow) * K + scol;

    float inv[16];
#pragma unroll
    for (int h = 0; h < 16; ++h) {
        float l0 = lsum[((size_t)b * 16 + h) * 2048 + q];
        float l1 = lsum[((size_t)(2 + b) * 16 + h) * 2048 + q];
        inv[h] = 1.f / (l0 + l1);
    }

    const int xorv = (lm >> 1) & 7;
    const int rA0 = wm * 64 + lm, rB0 = wn * 32 + lm;

    accf acc[2] = {zero16(), zero16()};

    // prologue: stage iter 0 (B via DMA, A via load+combine+ds_write)
    dma16(gb, &Bs[w * 512]);
    {
        bfr v0 = *(const bfr*)pa0;
        bfr v1 = *(const bfr*)pa1;
        const float iv = inv[0];
        bfr pk;
#pragma unroll
        for (int j = 0; j < 8; ++j)
            pk[j] = f2bf((bf2f(v0[j]) + bf2f(v1[j])) * iv);
        *(bfr*)&As[t * 8] = pk;
    }

#pragma unroll 1
    for (int it = 0; it < NIT; ++it) {
        const int p = it & 1;
        __syncthreads();  // drains buf-p DMA + ds_writes
        bfr v0, v1;
        const bool nxt = (it + 1 < NIT);
        if (nxt) {
            const int ktn = (it + 1) * 32;
            dma16(gb + ktn, &Bs[(1 - p) * 4096 + w * 512]);
            v0 = *(const bfr*)(pa0 + ktn);
            v1 = *(const bfr*)(pa1 + ktn);
        }
        const short* bA = &As[p * 4096];
        const short* bB = &Bs[p * 4096];
#pragma unroll
        for (int kk8 = 0; kk8 < 4; kk8 += 2) {
            bfr a0 = *(const bfr*)&bA[((rA0 * 4 + h2 + kk8) ^ xorv) * 8];
            bfr a1 = *(const bfr*)&bA[(((rA0 + 32) * 4 + h2 + kk8) ^ xorv) * 8];
            bfr b0 = *(const bfr*)&bB[((rB0 * 4 + h2 + kk8) ^ xorv) * 8];
            acc[0] = MFMA32(a0, b0, acc[0]);
            acc[1] = MFMA32(a1, b0, acc[1]);
        }
        if (nxt) {
            const float iv = inv[(it + 1) >> 1];  // h = kt>>6, iter-uniform
            bfr pk;
#pragma unroll
            for (int j = 0; j < 8; ++j)
                pk[j] = f2bf((bf2f(v0[j]) + bf2f(v1[j])) * iv);
            *(bfr*)&As[(1 - p) * 4096 + t * 8] = pk;
        }
    }

    const int n = n0 + wn * 32 + lm;
    const float bn = bias[n];
#pragma unroll
    for (int mt = 0; mt < 2; ++mt) {
        const int mbase = m0 + wm * 64 + mt * 32 + 4 * h2;
#pragma unroll
        for (int r = 0; r < 16; ++r) {
            const int m = mbase + (r & 3) + 8 * (r >> 2);
            out[(size_t)m * 1024 + n] = acc[mt][r] + bn;
        }
    }
}

// ---------- flash attention: R11 body, grid split into 2 dispatches -------
// Each dispatch: 512 blocks = 32 hidx x (8 qb x 2 split); qb += qhalf*8.
// Blocks fully independent -> splitting the grid is an identity transform;
// purpose is rocprof visibility (each half ~23us < other kernels).
__global__ __launch_bounds__(256, 3) void attn(
    const short* __restrict__ Qf, const short* __restrict__ Kf,
    const short* __restrict__ Vt, short* __restrict__ part,
    float* __restrict__ lsum, int qhalf) {
    __shared__ short smem[16384];  // 2 bufs x (K 4KB + V 4KB) = 32 KB
    const int bid = blockIdx.x;
    const int hidx = bid & 31, qs = bid >> 5;  // qs 0..15
    const int split = qs & 1, qb = (qs >> 1) + qhalf * 8;
    const int b = hidx >> 4, h = hidx & 15;
    const int lane = threadIdx.x & 63, wv = threadIdx.x >> 6;
    const int lm = lane & 31, h2 = lane >> 5;
    const bool hb = h2 != 0;
    const int q0 = qb * 128 + wv * 32;

    const short* qbase =
        Qf + ((size_t)(hidx * 64 + (q0 >> 5))) * 2048 + lane * 8;
    bfr qf[4];
#pragma unroll
    for (int kc = 0; kc < 4; ++kc) qf[kc] = *(const bfr*)(qbase + kc * 512);

    const short* khead = Kf + (size_t)hidx * 131072 + split * 65536;
    const short* vhead = Vt + (size_t)hidx * 131072 + split * 65536;
    const short* gsrc =
        ((wv < 2) ? (khead + wv * 2048) : (vhead + (wv - 2) * 2048)) + lane * 8;

#pragma unroll
    for (int i = 0; i < 4; ++i)
        dma16(gsrc + i * 512, &smem[wv * 2048 + i * 512]);

    accf oa0 = zero16(), oa1 = zero16();
    float la0 = 0.f, la1 = 0.f;

#pragma unroll 1
    for (int it = 0; it < 16; ++it) {
        const int p = it & 1;
        __syncthreads();  // buf p DMA drained (vmcnt(0) before s_barrier)
        if (it + 1 < 16) {
            const short* gn = gsrc + (size_t)(it + 1) * 4096;
            short* ln = &smem[(1 - p) * 8192 + wv * 2048];
#pragma unroll
            for (int i = 0; i < 4; ++i) dma16(gn + i * 512, ln + i * 512);
        }
        const short* kb = &smem[p * 8192];
        bfr kf0[4], kf1[4], vf0[4], vf1[4];
#pragma unroll
        for (int kc = 0; kc < 4; ++kc) {
            kf0[kc] = *(const bfr*)&kb[kc * 512 + lane * 8];
            kf1[kc] = *(const bfr*)&kb[2048 + kc * 512 + lane * 8];
            vf0[kc] = *(const bfr*)&kb[4096 + kc * 512 + lane * 8];
            vf1[kc] = *(const bfr*)&kb[6144 + kc * 512 + lane * 8];
        }
        accf s0 = zero16(), s1 = zero16();
#pragma unroll
        for (int kc = 0; kc < 4; ++kc) {
            s0 = MFMA32(kf0[kc], qf[kc], s0);
            s1 = MFMA32(kf1[kc], qf[kc], s1);
        }

#pragma unroll
        for (int i = 0; i < 16; ++i) s0[i] = fexp2(s0[i]);
#pragma unroll
        for (int i = 0; i < 16; ++i) s1[i] = fexp2(s1[i]);
#pragma unroll
        for (int i = 0; i < 16; ++i) {
            if (i & 1) la1 += s0[i] + s1[i];
            else       la0 += s0[i] + s1[i];
        }

        // packed half-swap transpose
        bfr pb[4];
#pragma unroll
        for (int kc = 0; kc < 4; ++kc) {
            const accf& s = (kc < 2) ? s0 : s1;
            const int base = 8 * (kc & 1);
            unsigned Lw0 = __builtin_amdgcn_perm(__float_as_uint(s[base + 1]),
                                                 __float_as_uint(s[base + 0]),
                                                 0x07060302u);
            unsigned Lw1 = __builtin_amdgcn_perm(__float_as_uint(s[base + 3]),
                                                 __float_as_uint(s[base + 2]),
                                                 0x07060302u);
            unsigned Hw0 = __builtin_amdgcn_perm(__float_as_uint(s[base + 5]),
                                                 __float_as_uint(s[base + 4]),
                                                 0x07060302u);
            unsigned Hw1 = __builtin_amdgcn_perm(__float_as_uint(s[base + 7]),
                                                 __float_as_uint(s[base + 6]),
                                                 0x07060302u);
            unsigned c0 = hb ? Lw0 : Hw0;
            unsigned c1 = hb ? Lw1 : Hw1;
            unsigned r0 = (unsigned)__shfl_xor((int)c0, 32);
            unsigned r1 = (unsigned)__shfl_xor((int)c1, 32);
            u4v pw = {hb ? r0 : Lw0, hb ? r1 : Lw1,
                      hb ? Hw0 : r0, hb ? Hw1 : r1};
            pb[kc] = __builtin_bit_cast(bfr, pw);
        }

#pragma unroll
        for (int kc = 0; kc < 4; ++kc) {
            oa0 = MFMA32(vf0[kc], pb[kc], oa0);
            oa1 = MFMA32(vf1[kc], pb[kc], oa1);
        }
    }

    float ls = la0 + la1;
    ls += __shfl_xor(ls, 32);
    if (!hb) lsum[((size_t)(split * 2 + b) * 16 + h) * 2048 + q0 + lm] = ls;

    short* orow = part + (size_t)split * 4194304 +
                  (size_t)(b * 2048 + q0 + lm) * 1024 + h * 64;
#pragma unroll
    for (int dt = 0; dt < 2; ++dt) {
        const accf& oa = dt ? oa1 : oa0;
#pragma unroll
        for (int g = 0; g < 4; ++g) {
            const int d0 = dt * 32 + 4 * h2 + 8 * g;
            s4v p = {f2bf(oa[4 * g + 0]), f2bf(oa[4 * g + 1]),
                     f2bf(oa[4 * g + 2]), f2bf(oa[4 * g + 3])};
            *(s4v*)(orow + d0) = p;
        }
    }
}

}  // namespace

extern "C" void kernel_launch(void* const* d_in, const int* in_sizes, int n_in,
                              void* d_out, int out_size, void* d_ws,
                              size_t ws_size, hipStream_t stream) {
    const float* x   = (const float*)d_in[0];
    const float* ctx = (const float*)d_in[1];
    const float* Wq  = (const float*)d_in[2];
    const float* bq  = (const float*)d_in[3];
    const float* Wk  = (const float*)d_in[4];
    const float* bk  = (const float*)d_in[5];
    const float* Wv  = (const float*)d_in[6];
    const float* bv  = (const float*)d_in[7];
    const float* Wo  = (const float*)d_in[8];
    const float* bo  = (const float*)d_in[9];

    short* xb  = (short*)d_ws;
    short* cb  = xb + (size_t)4096 * 1024;
    short* Wqt = cb + (size_t)4096 * 768;
    short* Wkt = Wqt + (size_t)1024 * 1024;
    short* Wvt = Wkt + (size_t)1024 * 768;
    short* Wot = Wvt + (size_t)1024 * 768;
    short* Qf  = Wot + (size_t)1024 * 1024;  // frag-order, pre-scaled
    short* Kf  = Qf + (size_t)4096 * 1024;   // frag-order
    short* Vt  = Kf + (size_t)4096 * 1024;   // frag-order V^T
    short* p0  = Vt + (size_t)4096 * 1024;   // split partials (unnormalized)
    short* p1  = p0 + (size_t)4096 * 1024;
    float* lsum = (float*)(p1 + (size_t)4096 * 1024);  // [2][2][16][2048]

    prep<<<8192, 256, 0, stream>>>(x, ctx, xb, cb, Wq, Wk, Wv, Wo,
                                   Wqt, Wkt, Wvt, Wot);

    const float qscale = 0.125f * 1.44269504088896f;
    gemm_qkv<<<768, 256, 0, stream>>>(xb, cb, Wqt, Wkt, Wvt,
                                      bq, bk, bv, Qf, Kf, Vt, qscale);

    attn<<<512, 256, 0, stream>>>(Qf, Kf, Vt, p0, lsum, 0);
    attn<<<512, 256, 0, stream>>>(Qf, Kf, Vt, p0, lsum, 1);

    gemm_out<<<256, 512, 0, stream>>>(p0, p1, lsum, Wot, bo, (float*)d_out);
}

// Round 9
// 215.080 us; speedup vs baseline: 1.0403x; 1.0294x over previous
//
#include <hip/hip_runtime.h>
#include <math.h>

// CrossAttention B=2,S=2048,E=1024,H=16,Dh=64,NC=768 — fp32 in/out.
// R9: XCD-colocating swizzle for GEMM grids + combine fused into gemm_out.
// R13/R16 (ran): attn pipeline variants flat ~46-48us — attn plateau
//   intrinsic to 64-row 4-wave block; reverted to R11 body.
// R17 (ran): attn split into 2 dispatches (instrumentation) exposed
//   gemm_qkv = 44.2us with MfmaUtil 17.6 / VALUBusy 13.6 / Occ 15.9% /
//   HBM 16% => latency/occupancy-bound (12 waves/CU, per-iter drain not
//   hidden). FETCH 30.8MB (swizzle works, vs 84.5 in R8), WRITE 24.6MB.
// R18: gemm_qkv 256thr/4w -> 512thr/8w at SAME grid/tile/LDS (gemm_out's
//   proven wave decomposition: wn 0..3, rB0=wn*32+lm, acc[2]): 24 waves/CU.
//   LDS layout byte-identical (slot t holds chunk t^((t>>3)&7), valid for
//   all 512 slots); 1 dma16/thread/operand. __launch_bounds__(512,6) caps
//   VGPR at 85 (acc halves to 32). attn split kept for profiling vis.

namespace {

typedef short bfr __attribute__((ext_vector_type(8)));   // 8 bf16 = 4 VGPR
typedef short s4v __attribute__((ext_vector_type(4)));
typedef unsigned u4v __attribute__((ext_vector_type(4)));
typedef float accf __attribute__((ext_vector_type(16)));

#define MFMA32(a, b, c) __builtin_amdgcn_mfma_f32_32x32x16_bf16(a, b, c, 0, 0, 0)

__device__ inline short f2bf(float f) {  // RNE
    unsigned u = __float_as_uint(f);
    u += 0x7fffu + ((u >> 16) & 1u);
    return (short)(u >> 16);
}
__device__ inline float bf2f(short s) {
    return __uint_as_float(((unsigned)(unsigned short)s) << 16);
}
__device__ inline float fexp2(float x) { return __builtin_amdgcn_exp2f(x); }
__device__ inline accf zero16() {
    accf z;
#pragma unroll
    for (int i = 0; i < 16; ++i) z[i] = 0.f;
    return z;
}
__device__ inline void dma16(const void* g, void* l) {
    __builtin_amdgcn_global_load_lds(
        (const __attribute__((address_space(1))) void*)g,
        (__attribute__((address_space(3))) void*)l, 16, 0, 0);
}

// ---------- prep: tobf (x,ctx) + all 4 weight transposes, one dispatch ----
__global__ __launch_bounds__(256) void prep(
    const float* __restrict__ x, const float* __restrict__ ctx,
    short* __restrict__ xb, short* __restrict__ cb,
    const float* __restrict__ Wq, const float* __restrict__ Wk,
    const float* __restrict__ Wv, const float* __restrict__ Wo,
    short* __restrict__ Wqt, short* __restrict__ Wkt,
    short* __restrict__ Wvt, short* __restrict__ Wot) {
    __shared__ short t[64][68];
    const int bx = blockIdx.x;
    if (bx < 7168) {  // elementwise fp32->bf16
        int i = bx * 256 + threadIdx.x;
        if (i < 1048576) {
            float4 v = ((const float4*)x)[i];
            s4v p = {f2bf(v.x), f2bf(v.y), f2bf(v.z), f2bf(v.w)};
            ((s4v*)xb)[i] = p;
        } else {
            int j = i - 1048576;
            float4 v = ((const float4*)ctx)[j];
            s4v p = {f2bf(v.x), f2bf(v.y), f2bf(v.z), f2bf(v.w)};
            ((s4v*)cb)[j] = p;
        }
        return;
    }
    const int idx = bx - 7168;  // 0..1023
    const int z = idx >> 8, gy = (idx >> 4) & 15, gx = idx & 15;
    const float* W;
    short* Wt;
    int K;
    switch (z) {
        case 0: W = Wq; Wt = Wqt; K = 1024; break;
        case 1: W = Wk; Wt = Wkt; K = 768; break;
        case 2: W = Wv; Wt = Wvt; K = 768; break;
        default: W = Wo; Wt = Wot; K = 1024; break;
    }
    const int k0 = gy * 64;
    if (k0 >= K) return;
    const int tid = threadIdx.x;
    const int n0 = gx * 64;
    const int kr = tid >> 4, nc = (tid & 15) * 4;
#pragma unroll
    for (int rep = 0; rep < 4; ++rep) {
        int k = kr + rep * 16;
        float4 v = *(const float4*)&W[(size_t)(k0 + k) * 1024 + n0 + nc];
        t[nc + 0][k] = f2bf(v.x);
        t[nc + 1][k] = f2bf(v.y);
        t[nc + 2][k] = f2bf(v.z);
        t[nc + 3][k] = f2bf(v.w);
    }
    __syncthreads();
    const int nr = tid >> 4, kc = (tid & 15) * 4;
#pragma unroll
    for (int rep = 0; rep < 4; ++rep) {
        int n = nr + rep * 16;
        s4v p = {t[n][kc], t[n][kc + 1], t[n][kc + 2], t[n][kc + 3]};
        *(s4v*)&Wt[(size_t)(n0 + n) * K + k0 + kc] = p;
    }
}

// ---------- fused Q/K/V projection GEMM, 512 thr / 8 waves (R18) ----------
// XCD-swizzled 1D grid (768): z = bid>>8; local = bid&255; m = local&31,
// n = local>>5 -> bid%8 == m%8 colocates A-sharing blocks per XCD.
// Wave decomposition as gemm_out: wm = w&1 (m-half), wn = w>>1 (n-quarter).
__global__ __launch_bounds__(512, 6) void gemm_qkv(
    const short* __restrict__ xb, const short* __restrict__ cb,
    const short* __restrict__ Wqt, const short* __restrict__ Wkt,
    const short* __restrict__ Wvt, const float* __restrict__ bq,
    const float* __restrict__ bk, const float* __restrict__ bv,
    short* __restrict__ Qf, short* __restrict__ Kf, short* __restrict__ Vt,
    float qscale) {
    const int bid = blockIdx.x;
    const int z = bid >> 8;
    const int local = bid & 255;
    const short* A  = (z == 0) ? xb : cb;
    const short* Bt = (z == 0) ? Wqt : ((z == 1) ? Wkt : Wvt);
    const float* bias = (z == 0) ? bq : ((z == 1) ? bk : bv);
    const int K = (z == 0) ? 1024 : 768;
    const int NIT = K / 32;
    const float scale = (z == 0) ? qscale : 1.f;
    short* out = (z == 0) ? Qf : ((z == 1) ? Kf : Vt);

    __shared__ short As[8192];  // 2 x 4096 (double buffer)
    __shared__ short Bs[8192];
    const int t = threadIdx.x, lane = t & 63, w = t >> 6;  // w 0..7
    const int lm = lane & 31, h2 = lane >> 5;
    const int wm = w & 1, wn = w >> 1;  // wn 0..3
    const int m0 = (local & 31) * 128, n0 = (local >> 5) * 128;

    // staging: slot t holds global chunk sigma(t) = t ^ ((t>>3)&7)
    // (involution; same layout rule as R11 for all 512 slots)
    const int st = t ^ ((t >> 3) & 7);
    const int srow = st >> 2, scol = (st & 3) * 8;
    const short* ga = A + (size_t)(m0 + srow) * K + scol;
    const short* gb = Bt + (size_t)(n0 + srow) * K + scol;

    // read: slot = chunk ^ xorv, chunk = row*4 + colchunk
    const int xorv = (lm >> 1) & 7;
    const int rA0 = wm * 64 + lm, rB0 = wn * 32 + lm;

    accf acc[2] = {zero16(), zero16()};

    // prologue: stage iter 0 into buf 0 (1 dma16/thread/operand)
    dma16(ga, &As[w * 512]);
    dma16(gb, &Bs[w * 512]);

#pragma unroll 1
    for (int it = 0; it < NIT; ++it) {
        const int p = it & 1;
        __syncthreads();  // drains DMA for buf p (vmcnt0 before s_barrier)
        if (it + 1 < NIT) {
            const int kt = (it + 1) * 32;
            dma16(ga + kt, &As[(1 - p) * 4096 + w * 512]);
            dma16(gb + kt, &Bs[(1 - p) * 4096 + w * 512]);
        }
        const short* bA = &As[p * 4096];
        const short* bB = &Bs[p * 4096];
#pragma unroll
        for (int kk8 = 0; kk8 < 4; kk8 += 2) {
            bfr a0 = *(const bfr*)&bA[((rA0 * 4 + h2 + kk8) ^ xorv) * 8];
            bfr a1 = *(const bfr*)&bA[(((rA0 + 32) * 4 + h2 + kk8) ^ xorv) * 8];
            bfr b0 = *(const bfr*)&bB[((rB0 * 4 + h2 + kk8) ^ xorv) * 8];
            acc[0] = MFMA32(a0, b0, acc[0]);
            acc[1] = MFMA32(a1, b0, acc[1]);
        }
    }

    const int n = n0 + wn * 32 + lm;
    const float bn = bias[n];
    const int hh = n >> 6, dd = n & 63;
#pragma unroll
    for (int mt = 0; mt < 2; ++mt) {
        const int mbase = m0 + wm * 64 + mt * 32 + 4 * h2;
        if (z != 2) {
            const int cb2 = (dd >> 4) * 512 + ((dd >> 3) & 1) * 256 + (dd & 7);
#pragma unroll
            for (int r = 0; r < 16; ++r) {
                const int m = mbase + (r & 3) + 8 * (r >> 2);
                const int bb = m >> 11, q = m & 2047;
                float v = (acc[mt][r] + bn) * scale;
                out[((size_t)((bb * 16 + hh) * 64 + (q >> 5))) * 2048 +
                    cb2 + (q & 31) * 8] = f2bf(v);
            }
        } else {
            const int dblk = dd >> 5, lmv = dd & 31;
#pragma unroll
            for (int g = 0; g < 4; ++g) {
                const int m = mbase + 8 * g;
                const int bb = m >> 11, s = m & 2047;
                const int kvt = s >> 6, kc = (s >> 4) & 3;
                const int h2v = (s >> 3) & 1, j0 = s & 7;
                s4v pq = {f2bf(acc[mt][4 * g + 0] + bn),
                          f2bf(acc[mt][4 * g + 1] + bn),
                          f2bf(acc[mt][4 * g + 2] + bn),
                          f2bf(acc[mt][4 * g + 3] + bn)};
                *(s4v*)(out +
                        ((size_t)(((bb * 16 + hh) * 32 + kvt) * 2 + dblk)) * 2048 +
                        kc * 512 + h2v * 256 + lmv * 8 + j0) = pq;
            }
        }
    }
}

// ---------- output GEMM with fused combine (512 thr, 8 waves) ----------
// A-tile = (p0+p1)*inv staged via explicit loads + ds_write (same swizzled
// slots); B via DMA. 1D grid 256, XCD swizzle m = bid&31.
__global__ __launch_bounds__(512) void gemm_out(
    const short* __restrict__ p0, const short* __restrict__ p1,
    const float* __restrict__ lsum, const short* __restrict__ Bt,
    const float* __restrict__ bias, float* __restrict__ out) {
    constexpr int K = 1024, NIT = 32;
    __shared__ short As[8192];  // 2 x 4096
    __shared__ short Bs[8192];
    const int t = threadIdx.x, lane = t & 63, w = t >> 6;  // w 0..7
    const int lm = lane & 31, h2 = lane >> 5;
    const int wm = w & 1, wn = w >> 1;
    const int bid = blockIdx.x;
    const int m0 = (bid & 31) * 128, n0 = (bid >> 5) * 128;

    const int st = t ^ ((t >> 3) & 7);
    const int srow = st >> 2, scol = (st & 3) * 8;  // 512 thr cover full tile
    const int gm = m0 + srow;
    const int b = gm >> 11, q = gm & 2047;
    const short* pa0 = p0 + (size_t)gm * 1024 + scol;
    const short* pa1 = p1 + (size_t)gm * 1024 + scol;
    const short* gb = Bt + (size_t)(n0 + srow) * K + scol;

    float inv[16];
#pragma unroll
    for (int h = 0; h < 16; ++h) {
        float l0 = lsum[((size_t)b * 16 + h) * 2048 + q];
        float l1 = lsum[((size_t)(2 + b) * 16 + h) * 2048 + q];
        inv[h] = 1.f / (l0 + l1);
    }

    const int xorv = (lm >> 1) & 7;
    const int rA0 = wm * 64 + lm, rB0 = wn * 32 + lm;

    accf acc[2] = {zero16(), zero16()};

    // prologue: stage iter 0 (B via DMA, A via load+combine+ds_write)
    dma16(gb, &Bs[w * 512]);
    {
        bfr v0 = *(const bfr*)pa0;
        bfr v1 = *(const bfr*)pa1;
        const float iv = inv[0];
        bfr pk;
#pragma unroll
        for (int j = 0; j < 8; ++j)
            pk[j] = f2bf((bf2f(v0[j]) + bf2f(v1[j])) * iv);
        *(bfr*)&As[t * 8] = pk;
    }

#pragma unroll 1
    for (int it = 0; it < NIT; ++it) {
        const int p = it & 1;
        __syncthreads();  // drains buf-p DMA + ds_writes
        bfr v0, v1;
        const bool nxt = (it + 1 < NIT);
        if (nxt) {
            const int ktn = (it + 1) * 32;
            dma16(gb + ktn, &Bs[(1 - p) * 4096 + w * 512]);
            v0 = *(const bfr*)(pa0 + ktn);
            v1 = *(const bfr*)(pa1 + ktn);
        }
        const short* bA = &As[p * 4096];
        const short* bB = &Bs[p * 4096];
#pragma unroll
        for (int kk8 = 0; kk8 < 4; kk8 += 2) {
            bfr a0 = *(const bfr*)&bA[((rA0 * 4 + h2 + kk8) ^ xorv) * 8];
            bfr a1 = *(const bfr*)&bA[(((rA0 + 32) * 4 + h2 + kk8) ^ xorv) * 8];
            bfr b0 = *(const bfr*)&bB[((rB0 * 4 + h2 + kk8) ^ xorv) * 8];
            acc[0] = MFMA32(a0, b0, acc[0]);
            acc[1] = MFMA32(a1, b0, acc[1]);
        }
        if (nxt) {
            const float iv = inv[(it + 1) >> 1];  // h = kt>>6, iter-uniform
            bfr pk;
#pragma unroll
            for (int j = 0; j < 8; ++j)
                pk[j] = f2bf((bf2f(v0[j]) + bf2f(v1[j])) * iv);
            *(bfr*)&As[(1 - p) * 4096 + t * 8] = pk;
        }
    }

    const int n = n0 + wn * 32 + lm;
    const float bn = bias[n];
#pragma unroll
    for (int mt = 0; mt < 2; ++mt) {
        const int mbase = m0 + wm * 64 + mt * 32 + 4 * h2;
#pragma unroll
        for (int r = 0; r < 16; ++r) {
            const int m = mbase + (r & 3) + 8 * (r >> 2);
            out[(size_t)m * 1024 + n] = acc[mt][r] + bn;
        }
    }
}

// ---------- flash attention: R11 body, grid split into 2 dispatches -------
// Each dispatch: 512 blocks = 32 hidx x (8 qb x 2 split); qb += qhalf*8.
// Blocks fully independent -> splitting the grid is an identity transform;
// purpose is rocprof visibility (each half ~23us < other kernels).
__global__ __launch_bounds__(256, 3) void attn(
    const short* __restrict__ Qf, const short* __restrict__ Kf,
    const short* __restrict__ Vt, short* __restrict__ part,
    float* __restrict__ lsum, int qhalf) {
    __shared__ short smem[16384];  // 2 bufs x (K 4KB + V 4KB) = 32 KB
    const int bid = blockIdx.x;
    const int hidx = bid & 31, qs = bid >> 5;  // qs 0..15
    const int split = qs & 1, qb = (qs >> 1) + qhalf * 8;
    const int b = hidx >> 4, h = hidx & 15;
    const int lane = threadIdx.x & 63, wv = threadIdx.x >> 6;
    const int lm = lane & 31, h2 = lane >> 5;
    const bool hb = h2 != 0;
    const int q0 = qb * 128 + wv * 32;

    const short* qbase =
        Qf + ((size_t)(hidx * 64 + (q0 >> 5))) * 2048 + lane * 8;
    bfr qf[4];
#pragma unroll
    for (int kc = 0; kc < 4; ++kc) qf[kc] = *(const bfr*)(qbase + kc * 512);

    const short* khead = Kf + (size_t)hidx * 131072 + split * 65536;
    const short* vhead = Vt + (size_t)hidx * 131072 + split * 65536;
    const short* gsrc =
        ((wv < 2) ? (khead + wv * 2048) : (vhead + (wv - 2) * 2048)) + lane * 8;

#pragma unroll
    for (int i = 0; i < 4; ++i)
        dma16(gsrc + i * 512, &smem[wv * 2048 + i * 512]);

    accf oa0 = zero16(), oa1 = zero16();
    float la0 = 0.f, la1 = 0.f;

#pragma unroll 1
    for (int it = 0; it < 16; ++it) {
        const int p = it & 1;
        __syncthreads();  // buf p DMA drained (vmcnt(0) before s_barrier)
        if (it + 1 < 16) {
            const short* gn = gsrc + (size_t)(it + 1) * 4096;
            short* ln = &smem[(1 - p) * 8192 + wv * 2048];
#pragma unroll
            for (int i = 0; i < 4; ++i) dma16(gn + i * 512, ln + i * 512);
        }
        const short* kb = &smem[p * 8192];
        bfr kf0[4], kf1[4], vf0[4], vf1[4];
#pragma unroll
        for (int kc = 0; kc < 4; ++kc) {
            kf0[kc] = *(const bfr*)&kb[kc * 512 + lane * 8];
            kf1[kc] = *(const bfr*)&kb[2048 + kc * 512 + lane * 8];
            vf0[kc] = *(const bfr*)&kb[4096 + kc * 512 + lane * 8];
            vf1[kc] = *(const bfr*)&kb[6144 + kc * 512 + lane * 8];
        }
        accf s0 = zero16(), s1 = zero16();
#pragma unroll
        for (int kc = 0; kc < 4; ++kc) {
            s0 = MFMA32(kf0[kc], qf[kc], s0);
            s1 = MFMA32(kf1[kc], qf[kc], s1);
        }

#pragma unroll
        for (int i = 0; i < 16; ++i) s0[i] = fexp2(s0[i]);
#pragma unroll
        for (int i = 0; i < 16; ++i) s1[i] = fexp2(s1[i]);
#pragma unroll
        for (int i = 0; i < 16; ++i) {
            if (i & 1) la1 += s0[i] + s1[i];
            else       la0 += s0[i] + s1[i];
        }

        // packed half-swap transpose
        bfr pb[4];
#pragma unroll
        for (int kc = 0; kc < 4; ++kc) {
            const accf& s = (kc < 2) ? s0 : s1;
            const int base = 8 * (kc & 1);
            unsigned Lw0 = __builtin_amdgcn_perm(__float_as_uint(s[base + 1]),
                                                 __float_as_uint(s[base + 0]),
                                                 0x07060302u);
            unsigned Lw1 = __builtin_amdgcn_perm(__float_as_uint(s[base + 3]),
                                                 __float_as_uint(s[base + 2]),
                                                 0x07060302u);
            unsigned Hw0 = __builtin_amdgcn_perm(__float_as_uint(s[base + 5]),
                                                 __float_as_uint(s[base + 4]),
                                                 0x07060302u);
            unsigned Hw1 = __builtin_amdgcn_perm(__float_as_uint(s[base + 7]),
                                                 __float_as_uint(s[base + 6]),
                                                 0x07060302u);
            unsigned c0 = hb ? Lw0 : Hw0;
            unsigned c1 = hb ? Lw1 : Hw1;
            unsigned r0 = (unsigned)__shfl_xor((int)c0, 32);
            unsigned r1 = (unsigned)__shfl_xor((int)c1, 32);
            u4v pw = {hb ? r0 : Lw0, hb ? r1 : Lw1,
                      hb ? Hw0 : r0, hb ? Hw1 : r1};
            pb[kc] = __builtin_bit_cast(bfr, pw);
        }

#pragma unroll
        for (int kc = 0; kc < 4; ++kc) {
            oa0 = MFMA32(vf0[kc], pb[kc], oa0);
            oa1 = MFMA32(vf1[kc], pb[kc], oa1);
        }
    }

    float ls = la0 + la1;
    ls += __shfl_xor(ls, 32);
    if (!hb) lsum[((size_t)(split * 2 + b) * 16 + h) * 2048 + q0 + lm] = ls;

    short* orow = part + (size_t)split * 4194304 +
                  (size_t)(b * 2048 + q0 + lm) * 1024 + h * 64;
#pragma unroll
    for (int dt = 0; dt < 2; ++dt) {
        const accf& oa = dt ? oa1 : oa0;
#pragma unroll
        for (int g = 0; g < 4; ++g) {
            const int d0 = dt * 32 + 4 * h2 + 8 * g;
            s4v p = {f2bf(oa[4 * g + 0]), f2bf(oa[4 * g + 1]),
                     f2bf(oa[4 * g + 2]), f2bf(oa[4 * g + 3])};
            *(s4v*)(orow + d0) = p;
        }
    }
}

}  // namespace

extern "C" void kernel_launch(void* const* d_in, const int* in_sizes, int n_in,
                              void* d_out, int out_size, void* d_ws,
                              size_t ws_size, hipStream_t stream) {
    const float* x   = (const float*)d_in[0];
    const float* ctx = (const float*)d_in[1];
    const float* Wq  = (const float*)d_in[2];
    const float* bq  = (const float*)d_in[3];
    const float* Wk  = (const float*)d_in[4];
    const float* bk  = (const float*)d_in[5];
    const float* Wv  = (const float*)d_in[6];
    const float* bv  = (const float*)d_in[7];
    const float* Wo  = (const float*)d_in[8];
    const float* bo  = (const float*)d_in[9];

    short* xb  = (short*)d_ws;
    short* cb  = xb + (size_t)4096 * 1024;
    short* Wqt = cb + (size_t)4096 * 768;
    short* Wkt = Wqt + (size_t)1024 * 1024;
    short* Wvt = Wkt + (size_t)1024 * 768;
    short* Wot = Wvt + (size_t)1024 * 768;
    short* Qf  = Wot + (size_t)1024 * 1024;  // frag-order, pre-scaled
    short* Kf  = Qf + (size_t)4096 * 1024;   // frag-order
    short* Vt  = Kf + (size_t)4096 * 1024;   // frag-order V^T
    short* p0  = Vt + (size_t)4096 * 1024;   // split partials (unnormalized)
    short* p1  = p0 + (size_t)4096 * 1024;
    float* lsum = (float*)(p1 + (size_t)4096 * 1024);  // [2][2][16][2048]

    prep<<<8192, 256, 0, stream>>>(x, ctx, xb, cb, Wq, Wk, Wv, Wo,
                                   Wqt, Wkt, Wvt, Wot);

    const float qscale = 0.125f * 1.44269504088896f;
    gemm_qkv<<<768, 512, 0, stream>>>(xb, cb, Wqt, Wkt, Wvt,
                                      bq, bk, bv, Qf, Kf, Vt, qscale);

    attn<<<512, 256, 0, stream>>>(Qf, Kf, Vt, p0, lsum, 0);
    attn<<<512, 256, 0, stream>>>(Qf, Kf, Vt, p0, lsum, 1);

    gemm_out<<<256, 512, 0, stream>>>(p0, p1, lsum, Wot, bo, (float*)d_out);
}

// Round 10
// 208.155 us; speedup vs baseline: 1.0749x; 1.0333x over previous
//
#include <hip/hip_runtime.h>
#include <math.h>

// CrossAttention B=2,S=2048,E=1024,H=16,Dh=64,NC=768 — fp32 in/out.
// Ledger: R11 216.4 (attn 46.4, qkv 44.2) | R13 attn counted-vmcnt null |
// R16 attn split4 -7us worse | R17 attn 2-dispatch split cost +5.0us (pure
// overhead) | R18 qkv 512thr/8w: 215.1, qkv ~38 (off top-5; fills 40.7 now
// mask everything -> A/B on total dur_us, noise ±0.5).
// R19: (1) attn merged back to ONE 1024-block dispatch (R11 body, 46.4us
//   proven) — reclaims R17's +5us split overhead. (2) gemm_qkv 3-deep
//   counted-vmcnt pipeline (R13's proven ledger, ported): qkv FETCH 30.8MB
//   = real HBM first-touch (~900cy); per-iter drain waits on loads issued
//   ~1 iter (~500cy) ago and 3 blocks/CU cover only ~450cy -> latency-bound.
//   3 bufs x 8KB (48KB LDS keeps 3 blocks/CU = 24 waves; 4-deep/64KB would
//   drop to 2 — m132 cliff). Per iter: vmcnt(2) -> raw s_barrier -> issue
//   batch it+2 -> compute. Wrapped tail keeps ledger exact; vmcnt(0) before
//   epilogue (no in-flight LDS-DMA at endpgm).

namespace {

typedef short bfr __attribute__((ext_vector_type(8)));   // 8 bf16 = 4 VGPR
typedef short s4v __attribute__((ext_vector_type(4)));
typedef unsigned u4v __attribute__((ext_vector_type(4)));
typedef float accf __attribute__((ext_vector_type(16)));

#define MFMA32(a, b, c) __builtin_amdgcn_mfma_f32_32x32x16_bf16(a, b, c, 0, 0, 0)

__device__ inline short f2bf(float f) {  // RNE
    unsigned u = __float_as_uint(f);
    u += 0x7fffu + ((u >> 16) & 1u);
    return (short)(u >> 16);
}
__device__ inline float bf2f(short s) {
    return __uint_as_float(((unsigned)(unsigned short)s) << 16);
}
__device__ inline float fexp2(float x) { return __builtin_amdgcn_exp2f(x); }
__device__ inline accf zero16() {
    accf z;
#pragma unroll
    for (int i = 0; i < 16; ++i) z[i] = 0.f;
    return z;
}
__device__ inline void dma16(const void* g, void* l) {
    __builtin_amdgcn_global_load_lds(
        (const __attribute__((address_space(1))) void*)g,
        (__attribute__((address_space(3))) void*)l, 16, 0, 0);
}

// ---------- prep: tobf (x,ctx) + all 4 weight transposes, one dispatch ----
__global__ __launch_bounds__(256) void prep(
    const float* __restrict__ x, const float* __restrict__ ctx,
    short* __restrict__ xb, short* __restrict__ cb,
    const float* __restrict__ Wq, const float* __restrict__ Wk,
    const float* __restrict__ Wv, const float* __restrict__ Wo,
    short* __restrict__ Wqt, short* __restrict__ Wkt,
    short* __restrict__ Wvt, short* __restrict__ Wot) {
    __shared__ short t[64][68];
    const int bx = blockIdx.x;
    if (bx < 7168) {  // elementwise fp32->bf16
        int i = bx * 256 + threadIdx.x;
        if (i < 1048576) {
            float4 v = ((const float4*)x)[i];
            s4v p = {f2bf(v.x), f2bf(v.y), f2bf(v.z), f2bf(v.w)};
            ((s4v*)xb)[i] = p;
        } else {
            int j = i - 1048576;
            float4 v = ((const float4*)ctx)[j];
            s4v p = {f2bf(v.x), f2bf(v.y), f2bf(v.z), f2bf(v.w)};
            ((s4v*)cb)[j] = p;
        }
        return;
    }
    const int idx = bx - 7168;  // 0..1023
    const int z = idx >> 8, gy = (idx >> 4) & 15, gx = idx & 15;
    const float* W;
    short* Wt;
    int K;
    switch (z) {
        case 0: W = Wq; Wt = Wqt; K = 1024; break;
        case 1: W = Wk; Wt = Wkt; K = 768; break;
        case 2: W = Wv; Wt = Wvt; K = 768; break;
        default: W = Wo; Wt = Wot; K = 1024; break;
    }
    const int k0 = gy * 64;
    if (k0 >= K) return;
    const int tid = threadIdx.x;
    const int n0 = gx * 64;
    const int kr = tid >> 4, nc = (tid & 15) * 4;
#pragma unroll
    for (int rep = 0; rep < 4; ++rep) {
        int k = kr + rep * 16;
        float4 v = *(const float4*)&W[(size_t)(k0 + k) * 1024 + n0 + nc];
        t[nc + 0][k] = f2bf(v.x);
        t[nc + 1][k] = f2bf(v.y);
        t[nc + 2][k] = f2bf(v.z);
        t[nc + 3][k] = f2bf(v.w);
    }
    __syncthreads();
    const int nr = tid >> 4, kc = (tid & 15) * 4;
#pragma unroll
    for (int rep = 0; rep < 4; ++rep) {
        int n = nr + rep * 16;
        s4v p = {t[n][kc], t[n][kc + 1], t[n][kc + 2], t[n][kc + 3]};
        *(s4v*)&Wt[(size_t)(n0 + n) * K + k0 + kc] = p;
    }
}

// ---------- fused Q/K/V projection GEMM, 512 thr / 8 waves ----------------
// R19: 3-deep counted-vmcnt pipeline. XCD-swizzled 1D grid (768):
// z = bid>>8; local = bid&255; m = local&31, n = local>>5.
__global__ __launch_bounds__(512, 6) void gemm_qkv(
    const short* __restrict__ xb, const short* __restrict__ cb,
    const short* __restrict__ Wqt, const short* __restrict__ Wkt,
    const short* __restrict__ Wvt, const float* __restrict__ bq,
    const float* __restrict__ bk, const float* __restrict__ bv,
    short* __restrict__ Qf, short* __restrict__ Kf, short* __restrict__ Vt,
    float qscale) {
    const int bid = blockIdx.x;
    const int z = bid >> 8;
    const int local = bid & 255;
    const short* A  = (z == 0) ? xb : cb;
    const short* Bt = (z == 0) ? Wqt : ((z == 1) ? Wkt : Wvt);
    const float* bias = (z == 0) ? bq : ((z == 1) ? bk : bv);
    const int K = (z == 0) ? 1024 : 768;
    const int NIT = K / 32;
    const float scale = (z == 0) ? qscale : 1.f;
    short* out = (z == 0) ? Qf : ((z == 1) ? Kf : Vt);

    __shared__ short As[12288];  // 3 x 4096 (triple buffer)
    __shared__ short Bs[12288];
    const int t = threadIdx.x, lane = t & 63, w = t >> 6;  // w 0..7
    const int lm = lane & 31, h2 = lane >> 5;
    const int wm = w & 1, wn = w >> 1;  // wn 0..3
    const int m0 = (local & 31) * 128, n0 = (local >> 5) * 128;

    // staging: slot t holds global chunk sigma(t) = t ^ ((t>>3)&7)
    const int st = t ^ ((t >> 3) & 7);
    const int srow = st >> 2, scol = (st & 3) * 8;
    const short* ga = A + (size_t)(m0 + srow) * K + scol;
    const short* gb = Bt + (size_t)(n0 + srow) * K + scol;

    // read: slot = chunk ^ xorv, chunk = row*4 + colchunk
    const int xorv = (lm >> 1) & 7;
    const int rA0 = wm * 64 + lm, rB0 = wn * 32 + lm;

    accf acc[2] = {zero16(), zero16()};

    // prologue: batches 0,1 into bufs 0,1 (4 loads/thread outstanding)
    dma16(ga, &As[w * 512]);
    dma16(gb, &Bs[w * 512]);
    __builtin_amdgcn_sched_barrier(0);
    dma16(ga + 32, &As[4096 + w * 512]);
    dma16(gb + 32, &Bs[4096 + w * 512]);
    __builtin_amdgcn_sched_barrier(0);

    int buf = 0;  // buffer holding batch it
#pragma unroll 1
    for (int it = 0; it < NIT; ++it) {
        // batch(it) issued 2 iters ago; newest 2 batches stay in flight.
        __builtin_amdgcn_sched_barrier(0);
        asm volatile("s_waitcnt vmcnt(2)" ::: "memory");
        __builtin_amdgcn_s_barrier();
        __builtin_amdgcn_sched_barrier(0);
        {
            // issue batch it+2 into buf((it+2)%3) — that buffer was last
            // read at iter it-1, strictly before the barrier above. Tail
            // wraps (dummy re-stage of an already-consumed batch) so the
            // outstanding count stays uniform and vmcnt(2) is exact.
            const int nx = (it + 2 >= NIT) ? (it + 2 - NIT) : (it + 2);
            const int nb = (buf + 2 >= 3) ? (buf - 1) : (buf + 2);
            dma16(ga + nx * 32, &As[nb * 4096 + w * 512]);
            dma16(gb + nx * 32, &Bs[nb * 4096 + w * 512]);
        }
        const short* bA = &As[buf * 4096];
        const short* bB = &Bs[buf * 4096];
#pragma unroll
        for (int kk8 = 0; kk8 < 4; kk8 += 2) {
            bfr a0 = *(const bfr*)&bA[((rA0 * 4 + h2 + kk8) ^ xorv) * 8];
            bfr a1 = *(const bfr*)&bA[(((rA0 + 32) * 4 + h2 + kk8) ^ xorv) * 8];
            bfr b0 = *(const bfr*)&bB[((rB0 * 4 + h2 + kk8) ^ xorv) * 8];
            acc[0] = MFMA32(a0, b0, acc[0]);
            acc[1] = MFMA32(a1, b0, acc[1]);
        }
        buf = (buf + 1 == 3) ? 0 : buf + 1;
    }
    // drain wrapped-tail DMAs before epilogue / endpgm (LDS reallocation).
    asm volatile("s_waitcnt vmcnt(0)" ::: "memory");
    __builtin_amdgcn_sched_barrier(0);

    const int n = n0 + wn * 32 + lm;
    const float bn = bias[n];
    const int hh = n >> 6, dd = n & 63;
#pragma unroll
    for (int mt = 0; mt < 2; ++mt) {
        const int mbase = m0 + wm * 64 + mt * 32 + 4 * h2;
        if (z != 2) {
            const int cb2 = (dd >> 4) * 512 + ((dd >> 3) & 1) * 256 + (dd & 7);
#pragma unroll
            for (int r = 0; r < 16; ++r) {
                const int m = mbase + (r & 3) + 8 * (r >> 2);
                const int bb = m >> 11, q = m & 2047;
                float v = (acc[mt][r] + bn) * scale;
                out[((size_t)((bb * 16 + hh) * 64 + (q >> 5))) * 2048 +
                    cb2 + (q & 31) * 8] = f2bf(v);
            }
        } else {
            const int dblk = dd >> 5, lmv = dd & 31;
#pragma unroll
            for (int g = 0; g < 4; ++g) {
                const int m = mbase + 8 * g;
                const int bb = m >> 11, s = m & 2047;
                const int kvt = s >> 6, kc = (s >> 4) & 3;
                const int h2v = (s >> 3) & 1, j0 = s & 7;
                s4v pq = {f2bf(acc[mt][4 * g + 0] + bn),
                          f2bf(acc[mt][4 * g + 1] + bn),
                          f2bf(acc[mt][4 * g + 2] + bn),
                          f2bf(acc[mt][4 * g + 3] + bn)};
                *(s4v*)(out +
                        ((size_t)(((bb * 16 + hh) * 32 + kvt) * 2 + dblk)) * 2048 +
                        kc * 512 + h2v * 256 + lmv * 8 + j0) = pq;
            }
        }
    }
}

// ---------- output GEMM with fused combine (512 thr, 8 waves) ----------
// A-tile = (p0+p1)*inv staged via explicit loads + ds_write (same swizzled
// slots); B via DMA. 1D grid 256, XCD swizzle m = bid&31.
__global__ __launch_bounds__(512) void gemm_out(
    const short* __restrict__ p0, const short* __restrict__ p1,
    const float* __restrict__ lsum, const short* __restrict__ Bt,
    const float* __restrict__ bias, float* __restrict__ out) {
    constexpr int K = 1024, NIT = 32;
    __shared__ short As[8192];  // 2 x 4096
    __shared__ short Bs[8192];
    const int t = threadIdx.x, lane = t & 63, w = t >> 6;  // w 0..7
    const int lm = lane & 31, h2 = lane >> 5;
    const int wm = w & 1, wn = w >> 1;
    const int bid = blockIdx.x;
    const int m0 = (bid & 31) * 128, n0 = (bid >> 5) * 128;

    const int st = t ^ ((t >> 3) & 7);
    const int srow = st >> 2, scol = (st & 3) * 8;  // 512 thr cover full tile
    const int gm = m0 + srow;
    const int b = gm >> 11, q = gm & 2047;
    const short* pa0 = p0 + (size_t)gm * 1024 + scol;
    const short* pa1 = p1 + (size_t)gm * 1024 + scol;
    const short* gb = Bt + (size_t)(n0 + srow) * K + scol;

    float inv[16];
#pragma unroll
    for (int h = 0; h < 16; ++h) {
        float l0 = lsum[((size_t)b * 16 + h) * 2048 + q];
        float l1 = lsum[((size_t)(2 + b) * 16 + h) * 2048 + q];
        inv[h] = 1.f / (l0 + l1);
    }

    const int xorv = (lm >> 1) & 7;
    const int rA0 = wm * 64 + lm, rB0 = wn * 32 + lm;

    accf acc[2] = {zero16(), zero16()};

    // prologue: stage iter 0 (B via DMA, A via load+combine+ds_write)
    dma16(gb, &Bs[w * 512]);
    {
        bfr v0 = *(const bfr*)pa0;
        bfr v1 = *(const bfr*)pa1;
        const float iv = inv[0];
        bfr pk;
#pragma unroll
        for (int j = 0; j < 8; ++j)
            pk[j] = f2bf((bf2f(v0[j]) + bf2f(v1[j])) * iv);
        *(bfr*)&As[t * 8] = pk;
    }

#pragma unroll 1
    for (int it = 0; it < NIT; ++it) {
        const int p = it & 1;
        __syncthreads();  // drains buf-p DMA + ds_writes
        bfr v0, v1;
        const bool nxt = (it + 1 < NIT);
        if (nxt) {
            const int ktn = (it + 1) * 32;
            dma16(gb + ktn, &Bs[(1 - p) * 4096 + w * 512]);
            v0 = *(const bfr*)(pa0 + ktn);
            v1 = *(const bfr*)(pa1 + ktn);
        }
        const short* bA = &As[p * 4096];
        const short* bB = &Bs[p * 4096];
#pragma unroll
        for (int kk8 = 0; kk8 < 4; kk8 += 2) {
            bfr a0 = *(const bfr*)&bA[((rA0 * 4 + h2 + kk8) ^ xorv) * 8];
            bfr a1 = *(const bfr*)&bA[(((rA0 + 32) * 4 + h2 + kk8) ^ xorv) * 8];
            bfr b0 = *(const bfr*)&bB[((rB0 * 4 + h2 + kk8) ^ xorv) * 8];
            acc[0] = MFMA32(a0, b0, acc[0]);
            acc[1] = MFMA32(a1, b0, acc[1]);
        }
        if (nxt) {
            const float iv = inv[(it + 1) >> 1];  // h = kt>>6, iter-uniform
            bfr pk;
#pragma unroll
            for (int j = 0; j < 8; ++j)
                pk[j] = f2bf((bf2f(v0[j]) + bf2f(v1[j])) * iv);
            *(bfr*)&As[(1 - p) * 4096 + t * 8] = pk;
        }
    }

    const int n = n0 + wn * 32 + lm;
    const float bn = bias[n];
#pragma unroll
    for (int mt = 0; mt < 2; ++mt) {
        const int mbase = m0 + wm * 64 + mt * 32 + 4 * h2;
#pragma unroll
        for (int r = 0; r < 16; ++r) {
            const int m = mbase + (r & 3) + 8 * (r >> 2);
            out[(size_t)m * 1024 + n] = acc[mt][r] + bn;
        }
    }
}

// ---------- flash attention: R11 body, single 1024-block dispatch ---------
__global__ __launch_bounds__(256, 3) void attn(
    const short* __restrict__ Qf, const short* __restrict__ Kf,
    const short* __restrict__ Vt, short* __restrict__ part,
    float* __restrict__ lsum) {
    __shared__ short smem[16384];  // 2 bufs x (K 4KB + V 4KB) = 32 KB
    const int bid = blockIdx.x;
    const int hidx = bid & 31, qs = bid >> 5;
    const int split = qs & 1, qb = qs >> 1;
    const int b = hidx >> 4, h = hidx & 15;
    const int lane = threadIdx.x & 63, wv = threadIdx.x >> 6;
    const int lm = lane & 31, h2 = lane >> 5;
    const bool hb = h2 != 0;
    const int q0 = qb * 128 + wv * 32;

    const short* qbase =
        Qf + ((size_t)(hidx * 64 + (q0 >> 5))) * 2048 + lane * 8;
    bfr qf[4];
#pragma unroll
    for (int kc = 0; kc < 4; ++kc) qf[kc] = *(const bfr*)(qbase + kc * 512);

    const short* khead = Kf + (size_t)hidx * 131072 + split * 65536;
    const short* vhead = Vt + (size_t)hidx * 131072 + split * 65536;
    const short* gsrc =
        ((wv < 2) ? (khead + wv * 2048) : (vhead + (wv - 2) * 2048)) + lane * 8;

#pragma unroll
    for (int i = 0; i < 4; ++i)
        dma16(gsrc + i * 512, &smem[wv * 2048 + i * 512]);

    accf oa0 = zero16(), oa1 = zero16();
    float la0 = 0.f, la1 = 0.f;

#pragma unroll 1
    for (int it = 0; it < 16; ++it) {
        const int p = it & 1;
        __syncthreads();  // buf p DMA drained (vmcnt(0) before s_barrier)
        if (it + 1 < 16) {
            const short* gn = gsrc + (size_t)(it + 1) * 4096;
            short* ln = &smem[(1 - p) * 8192 + wv * 2048];
#pragma unroll
            for (int i = 0; i < 4; ++i) dma16(gn + i * 512, ln + i * 512);
        }
        const short* kb = &smem[p * 8192];
        bfr kf0[4], kf1[4], vf0[4], vf1[4];
#pragma unroll
        for (int kc = 0; kc < 4; ++kc) {
            kf0[kc] = *(const bfr*)&kb[kc * 512 + lane * 8];
            kf1[kc] = *(const bfr*)&kb[2048 + kc * 512 + lane * 8];
            vf0[kc] = *(const bfr*)&kb[4096 + kc * 512 + lane * 8];
            vf1[kc] = *(const bfr*)&kb[6144 + kc * 512 + lane * 8];
        }
        accf s0 = zero16(), s1 = zero16();
#pragma unroll
        for (int kc = 0; kc < 4; ++kc) {
            s0 = MFMA32(kf0[kc], qf[kc], s0);
            s1 = MFMA32(kf1[kc], qf[kc], s1);
        }

#pragma unroll
        for (int i = 0; i < 16; ++i) s0[i] = fexp2(s0[i]);
#pragma unroll
        for (int i = 0; i < 16; ++i) s1[i] = fexp2(s1[i]);
#pragma unroll
        for (int i = 0; i < 16; ++i) {
            if (i & 1) la1 += s0[i] + s1[i];
            else       la0 += s0[i] + s1[i];
        }

        // packed half-swap transpose
        bfr pb[4];
#pragma unroll
        for (int kc = 0; kc < 4; ++kc) {
            const accf& s = (kc < 2) ? s0 : s1;
            const int base = 8 * (kc & 1);
            unsigned Lw0 = __builtin_amdgcn_perm(__float_as_uint(s[base + 1]),
                                                 __float_as_uint(s[base + 0]),
                                                 0x07060302u);
            unsigned Lw1 = __builtin_amdgcn_perm(__float_as_uint(s[base + 3]),
                                                 __float_as_uint(s[base + 2]),
                                                 0x07060302u);
            unsigned Hw0 = __builtin_amdgcn_perm(__float_as_uint(s[base + 5]),
                                                 __float_as_uint(s[base + 4]),
                                                 0x07060302u);
            unsigned Hw1 = __builtin_amdgcn_perm(__float_as_uint(s[base + 7]),
                                                 __float_as_uint(s[base + 6]),
                                                 0x07060302u);
            unsigned c0 = hb ? Lw0 : Hw0;
            unsigned c1 = hb ? Lw1 : Hw1;
            unsigned r0 = (unsigned)__shfl_xor((int)c0, 32);
            unsigned r1 = (unsigned)__shfl_xor((int)c1, 32);
            u4v pw = {hb ? r0 : Lw0, hb ? r1 : Lw1,
                      hb ? Hw0 : r0, hb ? Hw1 : r1};
            pb[kc] = __builtin_bit_cast(bfr, pw);
        }

#pragma unroll
        for (int kc = 0; kc < 4; ++kc) {
            oa0 = MFMA32(vf0[kc], pb[kc], oa0);
            oa1 = MFMA32(vf1[kc], pb[kc], oa1);
        }
    }

    float ls = la0 + la1;
    ls += __shfl_xor(ls, 32);
    if (!hb) lsum[((size_t)(split * 2 + b) * 16 + h) * 2048 + q0 + lm] = ls;

    short* orow = part + (size_t)split * 4194304 +
                  (size_t)(b * 2048 + q0 + lm) * 1024 + h * 64;
#pragma unroll
    for (int dt = 0; dt < 2; ++dt) {
        const accf& oa = dt ? oa1 : oa0;
#pragma unroll
        for (int g = 0; g < 4; ++g) {
            const int d0 = dt * 32 + 4 * h2 + 8 * g;
            s4v p = {f2bf(oa[4 * g + 0]), f2bf(oa[4 * g + 1]),
                     f2bf(oa[4 * g + 2]), f2bf(oa[4 * g + 3])};
            *(s4v*)(orow + d0) = p;
        }
    }
}

}  // namespace

extern "C" void kernel_launch(void* const* d_in, const int* in_sizes, int n_in,
                              void* d_out, int out_size, void* d_ws,
                              size_t ws_size, hipStream_t stream) {
    const float* x   = (const float*)d_in[0];
    const float* ctx = (const float*)d_in[1];
    const float* Wq  = (const float*)d_in[2];
    const float* bq  = (const float*)d_in[3];
    const float* Wk  = (const float*)d_in[4];
    const float* bk  = (const float*)d_in[5];
    const float* Wv  = (const float*)d_in[6];
    const float* bv  = (const float*)d_in[7];
    const float* Wo  = (const float*)d_in[8];
    const float* bo  = (const float*)d_in[9];

    short* xb  = (short*)d_ws;
    short* cb  = xb + (size_t)4096 * 1024;
    short* Wqt = cb + (size_t)4096 * 768;
    short* Wkt = Wqt + (size_t)1024 * 1024;
    short* Wvt = Wkt + (size_t)1024 * 768;
    short* Wot = Wvt + (size_t)1024 * 768;
    short* Qf  = Wot + (size_t)1024 * 1024;  // frag-order, pre-scaled
    short* Kf  = Qf + (size_t)4096 * 1024;   // frag-order
    short* Vt  = Kf + (size_t)4096 * 1024;   // frag-order V^T
    short* p0  = Vt + (size_t)4096 * 1024;   // split partials (unnormalized)
    short* p1  = p0 + (size_t)4096 * 1024;
    float* lsum = (float*)(p1 + (size_t)4096 * 1024);  // [2][2][16][2048]

    prep<<<8192, 256, 0, stream>>>(x, ctx, xb, cb, Wq, Wk, Wv, Wo,
                                   Wqt, Wkt, Wvt, Wot);

    const float qscale = 0.125f * 1.44269504088896f;
    gemm_qkv<<<768, 512, 0, stream>>>(xb, cb, Wqt, Wkt, Wvt,
                                      bq, bk, bv, Qf, Kf, Vt, qscale);

    attn<<<1024, 256, 0, stream>>>(Qf, Kf, Vt, p0, lsum);

    gemm_out<<<256, 512, 0, stream>>>(p0, p1, lsum, Wot, bo, (float*)d_out);
}